// Round 2
// baseline (16710.574 us; speedup 1.0000x reference)
//
#include <hip/hip_runtime.h>
#include <math.h>

// ---------------- device helpers ----------------
__device__ __forceinline__ float gelu_f(float x) {
    const float c = 0.7978845608028654f; // sqrt(2/pi)
    float x3 = x * x * x;
    float inner = c * (x + 0.044715f * x3);
    return 0.5f * x * (1.0f + tanhf(inner));
}

// ---------------- embed: x @ W_embed + b + pos, LIF ----------------
__global__ __launch_bounds__(256) void embed_kernel(
    const float* __restrict__ x, const float* __restrict__ We,
    const float* __restrict__ be, const float* __restrict__ pos,
    float* __restrict__ xemb) {
    int tok = blockIdx.x;            // 0..719  (b*90 + r)
    int d = threadIdx.x;             // 0..255
    __shared__ float xs[240];
    if (d < 240) xs[d] = x[(size_t)tok * 240 + d];
    __syncthreads();
    int r = tok % 90;
    double acc = 0.0;
    for (int s = 0; s < 240; ++s)
        acc = fma((double)xs[s], (double)We[(size_t)s * 256 + d], acc);
    float a = (float)acc + be[d] + pos[r * 256 + d];
    xemb[(size_t)tok * 256 + d] = (a > 1.0f) ? 1.0f : 0.0f;
}

// ---------------- simple copy ----------------
__global__ void copy_kernel(float* __restrict__ dst, const float* __restrict__ src, int n) {
    int i = blockIdx.x * 256 + threadIdx.x;
    if (i < n) dst[i] = src[i];
}

// ---------------- LayerNorm over D=256, one block per row ----------------
__global__ __launch_bounds__(256) void ln_kernel(
    const float* __restrict__ X, const float* __restrict__ g, const float* __restrict__ b,
    float* __restrict__ Y) {
    int row = blockIdx.x;
    int d = threadIdx.x;
    __shared__ float red[256];
    float v = X[(size_t)row * 256 + d];
    red[d] = v;
    __syncthreads();
    for (int s = 128; s > 0; s >>= 1) { if (d < s) red[d] += red[d + s]; __syncthreads(); }
    float mean = red[0] * (1.0f / 256.0f);
    __syncthreads();
    float dv = v - mean;
    red[d] = dv * dv;
    __syncthreads();
    for (int s = 128; s > 0; s >>= 1) { if (d < s) red[d] += red[d + s]; __syncthreads(); }
    float var = red[0] * (1.0f / 256.0f);
    float r = 1.0f / sqrtf(var + 1e-5f);
    Y[(size_t)row * 256 + d] = dv * r * g[d] + b[d];
}

// ---------------- final LN + LIF (teacher/student heads) ----------------
__global__ __launch_bounds__(256) void ln_lif_kernel(
    const float* __restrict__ X, const float* __restrict__ g, const float* __restrict__ b,
    float* __restrict__ Y) {
    int row = blockIdx.x;
    int d = threadIdx.x;
    __shared__ float red[256];
    float v = X[(size_t)row * 256 + d];
    red[d] = v;
    __syncthreads();
    for (int s = 128; s > 0; s >>= 1) { if (d < s) red[d] += red[d + s]; __syncthreads(); }
    float mean = red[0] * (1.0f / 256.0f);
    __syncthreads();
    float dv = v - mean;
    red[d] = dv * dv;
    __syncthreads();
    for (int s = 128; s > 0; s >>= 1) { if (d < s) red[d] += red[d + s]; __syncthreads(); }
    float var = red[0] * (1.0f / 256.0f);
    float r = 1.0f / sqrtf(var + 1e-5f);
    float val = dv * r * g[d] + b[d];
    Y[(size_t)row * 256 + d] = (val > 1.0f) ? 1.0f : 0.0f;
}

// ---------------- tiled f32 GEMM: C[M,N] = A[M,K] @ W[K,N] (+epilogue) ----------------
// A is packed (row stride K). W has row stride ldW; C (and R) row stride ldC.
// EPI 0: store; EPI 1: store acc + R (residual, in-place safe); EPI 2: store gelu(acc)
#define BM 64
#define BN 64
#define BK 16
template <int EPI>
__global__ __launch_bounds__(256) void gemm_kernel(
    const float* __restrict__ A, const float* __restrict__ W,
    float* __restrict__ C, const float* __restrict__ R,
    int M, int N, int K, int ldW, int ldC) {
    __shared__ float As[BK][BM + 4];
    __shared__ float Ws[BK][BN];
    int bm = blockIdx.y * BM;
    int bn = blockIdx.x * BN;
    int tid = threadIdx.x;
    int tx = tid & 15;   // n-dir
    int ty = tid >> 4;   // m-dir
    float acc[4][4] = {{0.f}};
    for (int k0 = 0; k0 < K; k0 += BK) {
        {
            int r = tid >> 2;           // 0..63 (m in tile)
            int kk = (tid & 3) * 4;     // 0,4,8,12
            int gm = bm + r;
            float4 v = make_float4(0.f, 0.f, 0.f, 0.f);
            if (gm < M) v = *(const float4*)(A + (size_t)gm * K + k0 + kk);
            As[kk + 0][r] = v.x; As[kk + 1][r] = v.y;
            As[kk + 2][r] = v.z; As[kk + 3][r] = v.w;
        }
        {
            int kk = tid >> 4;          // 0..15
            int n = (tid & 15) * 4;     // 0..60
            float4 v = *(const float4*)(W + (size_t)(k0 + kk) * ldW + bn + n);
            *(float4*)&Ws[kk][n] = v;
        }
        __syncthreads();
        #pragma unroll
        for (int k = 0; k < BK; ++k) {
            float a[4], w[4];
            #pragma unroll
            for (int i = 0; i < 4; ++i) a[i] = As[k][ty * 4 + i];
            #pragma unroll
            for (int j = 0; j < 4; ++j) w[j] = Ws[k][tx * 4 + j];
            #pragma unroll
            for (int i = 0; i < 4; ++i)
                #pragma unroll
                for (int j = 0; j < 4; ++j)
                    acc[i][j] = fmaf(a[i], w[j], acc[i][j]);
        }
        __syncthreads();
    }
    #pragma unroll
    for (int i = 0; i < 4; ++i) {
        int gm = bm + ty * 4 + i;
        if (gm >= M) continue;
        #pragma unroll
        for (int j = 0; j < 4; ++j) {
            int gn = bn + tx * 4 + j;
            float v = acc[i][j];
            if (EPI == 1) v += R[(size_t)gm * ldC + gn];
            if (EPI == 2) v = gelu_f(v);
            C[(size_t)gm * ldC + gn] = v;
        }
    }
}

// ---------------- attention: one block per (seq, head), N=90, hd=32 ----------------
__global__ __launch_bounds__(128) void attn_kernel(
    const float* __restrict__ QKV, float* __restrict__ AO, int causal) {
    int s = blockIdx.x >> 3;
    int h = blockIdx.x & 7;
    __shared__ float Ks[90][32];
    __shared__ float Vs[90][32];
    int tid = threadIdx.x;
    for (int i = tid; i < 90 * 32; i += 128) {
        int n = i >> 5, d = i & 31;
        size_t base = ((size_t)s * 90 + n) * 768 + h * 32;
        Ks[n][d] = QKV[base + 256 + d];
        Vs[n][d] = QKV[base + 512 + d];
    }
    __syncthreads();
    int q = tid;
    if (q >= 90) return;
    float qv[32];
    size_t qbase = ((size_t)s * 90 + q) * 768 + h * 32;
    #pragma unroll
    for (int d = 0; d < 32; ++d) qv[d] = QKV[qbase + d];
    const float sq = 5.656854249492380195f;  // sqrt(32)
    int kmax = causal ? (q + 1) : 90;
    // pass 1: max
    float m = -3.0e38f;
    for (int k = 0; k < kmax; ++k) {
        float sd = 0.f;
        #pragma unroll
        for (int d = 0; d < 32; ++d) sd = fmaf(qv[d], Ks[k][d], sd);
        sd /= sq;
        m = fmaxf(m, sd);
    }
    // pass 2: exp/sum/PV
    float sum = 0.f;
    float acc[32];
    #pragma unroll
    for (int d = 0; d < 32; ++d) acc[d] = 0.f;
    for (int k = 0; k < kmax; ++k) {
        float sd = 0.f;
        #pragma unroll
        for (int d = 0; d < 32; ++d) sd = fmaf(qv[d], Ks[k][d], sd);
        sd /= sq;
        float p = expf(sd - m);
        sum += p;
        #pragma unroll
        for (int d = 0; d < 32; ++d) acc[d] = fmaf(p, Vs[k][d], acc[d]);
    }
    size_t obase = ((size_t)s * 90 + q) * 256 + h * 32;
    #pragma unroll
    for (int d = 0; d < 32; ++d) AO[obase + d] = acc[d] / sum;
}

// ---------------- masks = lif(mask_token + pos) ----------------
__global__ void masks_kernel(const float* __restrict__ mt, const float* __restrict__ pos,
                             float* __restrict__ M) {
    int i = blockIdx.x * 256 + threadIdx.x;
    if (i >= 90 * 256) return;
    int d = i & 255;
    float v = mt[d] + pos[i];
    M[i] = (v > 1.0f) ? 1.0f : 0.0f;
}

// ---------------- build leave-one-out sequences for seq chunk [s0, s0+c) ----------------
__global__ void gather_kernel(const float* __restrict__ student, const float* __restrict__ masks,
                              float* __restrict__ X, int s0, int c) {
    int idx = blockIdx.x * 256 + threadIdx.x;
    if (idx >= c * 90 * 256) return;
    int d = idx & 255;
    int t = idx >> 8;        // token within chunk
    int j = t % 90;          // position in sequence
    int ls = t / 90;         // sequence within chunk
    int gs = s0 + ls;        // global sequence index (b*90 + r)
    int r = gs % 90;
    int b = gs / 90;
    float v;
    if (j == 89) {
        v = masks[r * 256 + d];
    } else {
        int src = (j < r) ? j : j + 1;
        v = student[((size_t)(b * 90 + src)) * 256 + d];
    }
    X[idx] = v;
}

// ---------------- extract pred last row + LIF; one block per sequence ----------------
__global__ __launch_bounds__(256) void extract_kernel(
    const float* __restrict__ X, float* __restrict__ predT, int s0) {
    int ls = blockIdx.x;
    int d = threadIdx.x;
    float v = X[((size_t)ls * 90 + 89) * 256 + d];
    predT[(size_t)(s0 + ls) * 256 + d] = (v > 1.0f) ? 1.0f : 0.0f;
}

// ---------------- decode: lif(T @ W_dec + b_dec) + row mean ----------------
__global__ __launch_bounds__(256) void decode_kernel(
    const float* __restrict__ T, const float* __restrict__ Wd, const float* __restrict__ bd,
    float* __restrict__ outseq, float* __restrict__ outmean) {
    int row = blockIdx.x;   // 0..719
    int n = threadIdx.x;
    __shared__ float ts[256];
    __shared__ float red[256];
    ts[n] = T[(size_t)row * 256 + n];
    __syncthreads();
    float sval = 0.f;
    if (n < 240) {
        double acc = 0.0;
        for (int k = 0; k < 256; ++k)
            acc = fma((double)ts[k], (double)Wd[(size_t)k * 240 + n], acc);
        float a = (float)acc;
        a += bd[n];
        sval = (a > 1.0f) ? 1.0f : 0.0f;
        outseq[(size_t)row * 240 + n] = sval;
    }
    red[n] = sval;
    __syncthreads();
    for (int s = 128; s > 0; s >>= 1) { if (n < s) red[n] += red[n + s]; __syncthreads(); }
    if (n == 0) outmean[row] = red[0] * (1.0f / 240.0f);
}

// ---------------- target passthrough + mean ----------------
__global__ __launch_bounds__(256) void target_kernel(
    const float* __restrict__ x, float* __restrict__ outseq, float* __restrict__ outmean) {
    int row = blockIdx.x;
    int n = threadIdx.x;
    __shared__ float red[256];
    float v = 0.f;
    if (n < 240) {
        v = x[(size_t)row * 240 + n];
        outseq[(size_t)row * 240 + n] = v;
    }
    red[n] = v;
    __syncthreads();
    for (int s = 128; s > 0; s >>= 1) { if (n < s) red[n] += red[n + s]; __syncthreads(); }
    if (n == 0) outmean[row] = red[0] * (1.0f / 240.0f);
}

// ---------------- host ----------------
extern "C" void kernel_launch(void* const* d_in, const int* in_sizes, int n_in,
                              void* d_out, int out_size, void* d_ws, size_t ws_size,
                              hipStream_t stream) {
    const float* x   = (const float*)d_in[0];
    const float* We  = (const float*)d_in[1];
    const float* be  = (const float*)d_in[2];
    const float* pos = (const float*)d_in[3];
    const float* mt  = (const float*)d_in[4];
    const float* ng  = (const float*)d_in[5];
    const float* nb  = (const float*)d_in[6];
    const float* Wd  = (const float*)d_in[7];
    const float* bd  = (const float*)d_in[8];
    const float* prm[3][6];
    for (int g = 0; g < 3; ++g)
        for (int k = 0; k < 6; ++k)
            prm[g][k] = (const float*)d_in[9 + g * 6 + k];
    // prm[g]: 0=qkv 1=out 2=ln1 3=ff1 4=ff2 5=ln2 ; g: 0=t 1=s 2=p

    float* wp = (float*)d_ws;
    auto alloc = [&](size_t n) { float* q = wp; wp += n; return q; };
    float* x_emb   = alloc(720 * 256);
    float* teacher = alloc(720 * 256);
    float* student = alloc(720 * 256);
    float* predT   = alloc(720 * 256);
    float* masksb  = alloc(90 * 256);
    size_t fixed = (size_t)(wp - (float*)d_ws);

    // per-token chunk scratch: X(256) + Xn/AO(256) + QKV(768) + Hc(256) = 1536 floats
    size_t avail = ws_size / 4;
    size_t per_seq = 90 * 1536;
    long ns_l = 1;
    if (avail > fixed + per_seq) ns_l = (long)((avail - fixed) / per_seq);
    int ns = (int)(ns_l < 1 ? 1 : (ns_l > 720 ? 720 : ns_l));
    int T_max = ns * 90;
    float* X   = alloc((size_t)T_max * 256);
    float* Xn  = alloc((size_t)T_max * 256);   // also used as attention output
    float* QKV = alloc((size_t)T_max * 768);
    float* Hc  = alloc((size_t)T_max * 256);

    float* out = (float*)d_out;

    embed_kernel<<<720, 256, 0, stream>>>(x, We, be, pos, x_emb);
    masks_kernel<<<90, 256, 0, stream>>>(mt, pos, masksb);

    auto run_layer = [&](int T, int c, const float* qkv, const float* wo,
                         const float* ln1, const float* ff1, const float* ff2,
                         const float* ln2, int causal) {
        int gy = (T + 63) / 64;
        ln_kernel<<<T, 256, 0, stream>>>(X, ln1, ln1 + 256, Xn);
        { dim3 g(768 / 64, gy);
          gemm_kernel<0><<<g, 256, 0, stream>>>(Xn, qkv, QKV, nullptr, T, 768, 256, 768, 768); }
        attn_kernel<<<c * 8, 128, 0, stream>>>(QKV, Xn, causal);
        { dim3 g(4, gy);
          gemm_kernel<1><<<g, 256, 0, stream>>>(Xn, wo, X, X, T, 256, 256, 256, 256); }
        ln_kernel<<<T, 256, 0, stream>>>(X, ln2, ln2 + 256, Xn);
        for (int kc = 0; kc < 4; ++kc) {
            dim3 g(4, gy);
            gemm_kernel<2><<<g, 256, 0, stream>>>(Xn, ff1 + kc * 256, Hc, nullptr,
                                                  T, 256, 256, 1024, 256);
            gemm_kernel<1><<<g, 256, 0, stream>>>(Hc, ff2 + (size_t)kc * 256 * 256, X, X,
                                                  T, 256, 256, 256, 256);
        }
    };

    // ---- teacher (gi=0) then student (gi=1), both from x_emb, chunked over 8 sequences ----
    int nse = ns < 8 ? ns : 8;
    for (int gi = 0; gi < 2; ++gi) {
        for (int s0 = 0; s0 < 8; s0 += nse) {
            int c = (8 - s0) < nse ? (8 - s0) : nse;
            int T = c * 90;
            copy_kernel<<<(T * 256 + 255) / 256, 256, 0, stream>>>(
                X, x_emb + (size_t)s0 * 90 * 256, T * 256);
            for (int l = 0; l < 8; ++l)
                run_layer(T, c,
                          prm[gi][0] + (size_t)l * 256 * 768,
                          prm[gi][1] + (size_t)l * 256 * 256,
                          prm[gi][2] + (size_t)l * 512,
                          prm[gi][3] + (size_t)l * 256 * 1024,
                          prm[gi][4] + (size_t)l * 1024 * 256,
                          prm[gi][5] + (size_t)l * 512, 0);
            ln_lif_kernel<<<T, 256, 0, stream>>>(
                X, ng, nb, (gi == 0 ? teacher : student) + (size_t)s0 * 90 * 256);
        }
    }

    // ---- predictor: 720 causal sequences of length 90, chunked by ns ----
    for (int s0 = 0; s0 < 720; s0 += ns) {
        int c = (720 - s0) < ns ? (720 - s0) : ns;
        int T = c * 90;
        gather_kernel<<<(T * 256 + 255) / 256, 256, 0, stream>>>(student, masksb, X, s0, c);
        for (int l = 0; l < 6; ++l)
            run_layer(T, c,
                      prm[2][0] + (size_t)l * 256 * 768,
                      prm[2][1] + (size_t)l * 256 * 256,
                      prm[2][2] + (size_t)l * 512,
                      prm[2][3] + (size_t)l * 256 * 1024,
                      prm[2][4] + (size_t)l * 1024 * 256,
                      prm[2][5] + (size_t)l * 512, 1);
        extract_kernel<<<c, 256, 0, stream>>>(X, predT, s0);
    }

    decode_kernel<<<720, 256, 0, stream>>>(predT, Wd, bd, out + 0, out + 518400);
    decode_kernel<<<720, 256, 0, stream>>>(teacher, Wd, bd, out + 172800, out + 519120);
    target_kernel<<<720, 256, 0, stream>>>(x, out + 345600, out + 519840);
}